// Round 1
// baseline (520.504 us; speedup 1.0000x reference)
//
#include <hip/hip_runtime.h>
#include <math.h>

#define T_DIM   1024
#define B_DIM   32
#define N_FEAT  1024
#define KW      3
#define NT      16                 // t-chunks for weighted-V pass
#define T_PER   (T_DIM / NT)       // 64
#define EPS     1e-6f

// ---------------------------------------------------------------------------
// Kernel 1/2: generic GEMV  out[b,m] = dot(x[b,:], W[m,:]) + bias[m]
// One wave (64 lanes) per output element; float4 coalesced reads of W row.
// ---------------------------------------------------------------------------
__global__ void __launch_bounds__(256) gemv_kernel(
    const float* __restrict__ x, const float* __restrict__ W,
    const float* __restrict__ bias, float* __restrict__ out,
    int N, int M) {
  int gtid = blockIdx.x * blockDim.x + threadIdx.x;
  int wid  = gtid >> 6;
  int lane = threadIdx.x & 63;
  int total = B_DIM * M;
  if (wid >= total) return;
  int b = wid / M, m = wid % M;
  const float4* xr = (const float4*)(x + (size_t)b * N);
  const float4* wr = (const float4*)(W + (size_t)m * N);
  float acc = 0.f;
  int n4 = N >> 2;
  for (int i = lane; i < n4; i += 64) {
    float4 xv = xr[i], wv = wr[i];
    acc += xv.x * wv.x + xv.y * wv.y + xv.z * wv.z + xv.w * wv.w;
  }
#pragma unroll
  for (int off = 32; off > 0; off >>= 1) acc += __shfl_down(acc, off, 64);
  if (lane == 0) out[wid] = acc + bias[m];
}

// ---------------------------------------------------------------------------
// Kernel 3: per-(t,b) row dots over k1 and k2 (the 256 MiB read pass).
//   a1[t,b]    = sum_a tanh(sa_q[b,a] + k1[t,b,a]) * a1_w[a] + a1_b
//   s[t,b,w]   = sum_c k2[t,b,c] * kern[b,c,w]        (w = 0..2)
// One 256-thread block per (t*B+b); each thread handles 4 contiguous feats.
// ---------------------------------------------------------------------------
__global__ void __launch_bounds__(256) row_dots_kernel(
    const float* __restrict__ k1, const float* __restrict__ k2,
    const float* __restrict__ sa_q, const float* __restrict__ a1_w,
    const float* __restrict__ kern, const float* __restrict__ a1_b,
    float* __restrict__ a1_out, float* __restrict__ s_out) {
  int blk = blockIdx.x;            // t*B + b
  int b   = blk % B_DIM;
  int tid = threadIdx.x;
  size_t row = (size_t)blk * N_FEAT + tid * 4;

  float4 k1v = *(const float4*)(k1 + row);
  float4 sqv = *(const float4*)(sa_q + (size_t)b * N_FEAT + tid * 4);
  float4 awv = *(const float4*)(a1_w + tid * 4);
  float p1 = tanhf(k1v.x + sqv.x) * awv.x
           + tanhf(k1v.y + sqv.y) * awv.y
           + tanhf(k1v.z + sqv.z) * awv.z
           + tanhf(k1v.w + sqv.w) * awv.w;

  float4 k2v = *(const float4*)(k2 + row);
  const float* kb = kern + (size_t)b * (N_FEAT * KW) + (size_t)tid * 4 * KW;
  float4 ka = *(const float4*)(kb);
  float4 kc = *(const float4*)(kb + 4);
  float4 kd = *(const float4*)(kb + 8);
  float kk[12] = {ka.x, ka.y, ka.z, ka.w, kc.x, kc.y, kc.z, kc.w,
                  kd.x, kd.y, kd.z, kd.w};
  float s0 = k2v.x * kk[0] + k2v.y * kk[3] + k2v.z * kk[6] + k2v.w * kk[9];
  float s1 = k2v.x * kk[1] + k2v.y * kk[4] + k2v.z * kk[7] + k2v.w * kk[10];
  float s2 = k2v.x * kk[2] + k2v.y * kk[5] + k2v.z * kk[8] + k2v.w * kk[11];

  // block reduce 4 values across 4 waves
  float vals[4] = {p1, s0, s1, s2};
#pragma unroll
  for (int off = 32; off > 0; off >>= 1) {
#pragma unroll
    for (int j = 0; j < 4; j++) vals[j] += __shfl_down(vals[j], off, 64);
  }
  __shared__ float red[4][4];
  int wave = tid >> 6, lane = tid & 63;
  if (lane == 0) {
#pragma unroll
    for (int j = 0; j < 4; j++) red[wave][j] = vals[j];
  }
  __syncthreads();
  if (tid == 0) {
    float r0 = red[0][0] + red[1][0] + red[2][0] + red[3][0];
    float r1 = red[0][1] + red[1][1] + red[2][1] + red[3][1];
    float r2 = red[0][2] + red[1][2] + red[2][2] + red[3][2];
    float r3 = red[0][3] + red[1][3] + red[2][3] + red[3][3];
    a1_out[blk] = r0 + a1_b[0];
    s_out[(size_t)blk * 3 + 0] = r1;
    s_out[(size_t)blk * 3 + 1] = r2;
    s_out[(size_t)blk * 3 + 2] = r3;
  }
}

// ---------------------------------------------------------------------------
// Block reduce helper (256 threads = 4 waves), broadcast result to all.
// ---------------------------------------------------------------------------
__device__ __forceinline__ float block_reduce_256(float v, bool is_max,
                                                  float* sm /*[4]*/) {
#pragma unroll
  for (int off = 32; off > 0; off >>= 1) {
    float o = __shfl_down(v, off, 64);
    v = is_max ? fmaxf(v, o) : v + o;
  }
  int wave = threadIdx.x >> 6;
  if ((threadIdx.x & 63) == 0) sm[wave] = v;
  __syncthreads();
  float r = is_max ? fmaxf(fmaxf(sm[0], sm[1]), fmaxf(sm[2], sm[3]))
                   : sm[0] + sm[1] + sm[2] + sm[3];
  __syncthreads();
  return r;
}

// ---------------------------------------------------------------------------
// Kernel 4: masked softmax over T for both paths. One block per b.
//   a2[t,b] = s[t-1,b,0] + s[t,b,1] + s[t+1,b,2]  (zero pad at edges)
// ---------------------------------------------------------------------------
__global__ void __launch_bounds__(256) softmax_kernel(
    const float* __restrict__ a1, const float* __restrict__ s,
    const float* __restrict__ k_mask,
    float* __restrict__ e1, float* __restrict__ e2) {
  int b = blockIdx.x;
  int tid = threadIdx.x;
  __shared__ float sm[4];

  float x1[4], x2[4], mk[4];
#pragma unroll
  for (int k = 0; k < 4; k++) {
    int t = tid + k * 256;
    x1[k] = a1[(size_t)t * B_DIM + b];
    float sl = (t > 0)         ? s[((size_t)(t - 1) * B_DIM + b) * 3 + 0] : 0.f;
    float sc =                   s[((size_t)t       * B_DIM + b) * 3 + 1];
    float sr = (t < T_DIM - 1) ? s[((size_t)(t + 1) * B_DIM + b) * 3 + 2] : 0.f;
    x2[k] = sl + sc + sr;
    mk[k] = k_mask[(size_t)t * B_DIM + b];
  }
  float m1 = fmaxf(fmaxf(x1[0], x1[1]), fmaxf(x1[2], x1[3]));
  float m2 = fmaxf(fmaxf(x2[0], x2[1]), fmaxf(x2[2], x2[3]));
  m1 = block_reduce_256(m1, true, sm);
  m2 = block_reduce_256(m2, true, sm);

  float v1[4], v2[4], sum1 = 0.f, sum2 = 0.f;
#pragma unroll
  for (int k = 0; k < 4; k++) {
    v1[k] = expf(x1[k] - m1) * mk[k];
    v2[k] = expf(x2[k] - m2) * mk[k];
    sum1 += v1[k];
    sum2 += v2[k];
  }
  sum1 = block_reduce_256(sum1, false, sm);
  sum2 = block_reduce_256(sum2, false, sm);
  float i1 = 1.f / sum1, i2 = 1.f / sum2;
#pragma unroll
  for (int k = 0; k < 4; k++) {
    int t = tid + k * 256;
    e1[(size_t)t * B_DIM + b] = v1[k] * i1;
    e2[(size_t)t * B_DIM + b] = v2[k] * i2;
  }
}

// ---------------------------------------------------------------------------
// Kernel 5: weighted sum over V for both paths (the other 256 MiB pass).
// grid = (B, NT); 256 threads x float4 = all 1024 feats; loop 64 t's.
// ---------------------------------------------------------------------------
__global__ void __launch_bounds__(256) weighted_v_kernel(
    const float* __restrict__ v1, const float* __restrict__ v2,
    const float* __restrict__ e1, const float* __restrict__ e2,
    float* __restrict__ partial) {
  int b  = blockIdx.x;
  int tc = blockIdx.y;
  int tid = threadIdx.x;
  __shared__ float se1[T_PER], se2[T_PER];
  if (tid < T_PER)
    se1[tid] = e1[(size_t)(tc * T_PER + tid) * B_DIM + b];
  else if (tid < 2 * T_PER)
    se2[tid - T_PER] = e2[(size_t)(tc * T_PER + (tid - T_PER)) * B_DIM + b];
  __syncthreads();

  float4 acc1 = {0.f, 0.f, 0.f, 0.f}, acc2 = {0.f, 0.f, 0.f, 0.f};
  size_t dofs = (size_t)tid * 4;
#pragma unroll 4
  for (int i = 0; i < T_PER; i++) {
    size_t row = ((size_t)(tc * T_PER + i) * B_DIM + b) * N_FEAT + dofs;
    float4 a = *(const float4*)(v1 + row);
    float4 c = *(const float4*)(v2 + row);
    float w1 = se1[i], w2 = se2[i];
    acc1.x += w1 * a.x; acc1.y += w1 * a.y; acc1.z += w1 * a.z; acc1.w += w1 * a.w;
    acc2.x += w2 * c.x; acc2.y += w2 * c.y; acc2.z += w2 * c.z; acc2.w += w2 * c.w;
  }
  size_t o1 = ((size_t)(0 * NT + tc) * B_DIM + b) * N_FEAT + dofs;
  size_t o2 = ((size_t)(1 * NT + tc) * B_DIM + b) * N_FEAT + dofs;
  *(float4*)(partial + o1) = acc1;
  *(float4*)(partial + o2) = acc2;
}

// ---------------------------------------------------------------------------
// Kernel 6: reduce partials, add paths, LayerNorm over feature dim.
// One block per b, 1024 threads (16 waves).
// ---------------------------------------------------------------------------
__device__ __forceinline__ float block_reduce_sum_1024(float v, float* sm) {
#pragma unroll
  for (int off = 32; off > 0; off >>= 1) v += __shfl_down(v, off, 64);
  int wave = threadIdx.x >> 6;
  if ((threadIdx.x & 63) == 0) sm[wave] = v;
  __syncthreads();
  float tot = 0.f;
#pragma unroll
  for (int i = 0; i < 16; i++) tot += sm[i];
  __syncthreads();
  return tot;
}

__global__ void __launch_bounds__(1024) ln_kernel(
    const float* __restrict__ partial, const float* __restrict__ ln_g,
    const float* __restrict__ ln_b, float* __restrict__ out) {
  int b = blockIdx.x;
  int d = threadIdx.x;
  __shared__ float sm[16];
  float x = 0.f;
#pragma unroll
  for (int j = 0; j < 2 * NT; j++)
    x += partial[((size_t)j * B_DIM + b) * N_FEAT + d];
  float ssum = block_reduce_sum_1024(x, sm);
  float mu = ssum * (1.f / N_FEAT);
  float dx = x - mu;
  float vsum = block_reduce_sum_1024(dx * dx, sm);
  float inv = rsqrtf(vsum * (1.f / N_FEAT) + EPS);
  out[(size_t)b * N_FEAT + d] = dx * inv * ln_g[d] + ln_b[d];
}

// ---------------------------------------------------------------------------
extern "C" void kernel_launch(void* const* d_in, const int* in_sizes, int n_in,
                              void* d_out, int out_size, void* d_ws, size_t ws_size,
                              hipStream_t stream) {
  const float* q1     = (const float*)d_in[0];
  const float* k1     = (const float*)d_in[1];
  const float* v1     = (const float*)d_in[2];
  const float* q2     = (const float*)d_in[3];
  const float* k2     = (const float*)d_in[4];
  const float* v2     = (const float*)d_in[5];
  const float* k_mask = (const float*)d_in[6];
  const float* sa_w   = (const float*)d_in[7];
  const float* sa_b   = (const float*)d_in[8];
  const float* a1_w   = (const float*)d_in[9];
  const float* a1_b   = (const float*)d_in[10];
  const float* qk_w   = (const float*)d_in[11];
  const float* qk_b   = (const float*)d_in[12];
  const float* ln_g   = (const float*)d_in[13];
  const float* ln_bp  = (const float*)d_in[14];
  float* out = (float*)d_out;
  float* ws  = (float*)d_ws;

  // ws layout (floats)
  float* sa_q    = ws;                       // 32768
  float* kern    = sa_q + 32768;             // 98304
  float* s       = kern + 98304;             // 98304  [t][b][w]
  float* a1      = s + 98304;                // 32768  [t][b]
  float* e1      = a1 + 32768;               // 32768
  float* e2      = e1 + 32768;               // 32768
  float* partial = e2 + 32768;               // 2*NT*B*N = 1048576 (4 MiB)

  // 1) sa_q = q1 @ sa_w.T + sa_b        (B x 1024, 32768 waves)
  gemv_kernel<<<dim3((B_DIM * 1024) >> 2), 256, 0, stream>>>(
      q1, sa_w, sa_b, sa_q, N_FEAT, 1024);
  // 2) kern = q2 @ qk_w.T + qk_b        (B x 3072)
  gemv_kernel<<<dim3((B_DIM * 3072) >> 2), 256, 0, stream>>>(
      q2, qk_w, qk_b, kern, N_FEAT, 3072);
  // 3) a1 + conv taps s                  (reads k1, k2: 256 MiB)
  row_dots_kernel<<<dim3(T_DIM * B_DIM), 256, 0, stream>>>(
      k1, k2, sa_q, a1_w, kern, a1_b, a1, s);
  // 4) softmax both paths
  softmax_kernel<<<dim3(B_DIM), 256, 0, stream>>>(a1, s, k_mask, e1, e2);
  // 5) weighted V sums                   (reads v1, v2: 256 MiB)
  weighted_v_kernel<<<dim3(B_DIM, NT), 256, 0, stream>>>(v1, v2, e1, e2, partial);
  // 6) combine + LayerNorm
  ln_kernel<<<dim3(B_DIM), 1024, 0, stream>>>(partial, ln_g, ln_bp, out);
}